// Round 5
// baseline (2700.813 us; speedup 1.0000x reference)
//
#include <hip/hip_runtime.h>
#include <hip/hip_bf16.h>
#include <stdint.h>

// ContinuousEpisodicVLM: 3-step episodic retrieval loop.
// bf16 MFMA candidate generation (sampled-threshold filter) + bf16-top-64
// preselect + exact f32 rescore + exact top-50 softmax message.
// GEMM: 128x128 tile, BK=64, double-buffered LDS (2-phase counted-vmcnt
// pipeline), 4 M-tiles per block (mode 0), pre-swizzled global -> linear
// global_load_lds -> swizzled ds_read_b128 (zero bank conflicts).

typedef __attribute__((ext_vector_type(8))) short short8;
typedef __attribute__((ext_vector_type(4))) float f32x4;

#define DIM    768
#define NPATCH 2048
#define NMEM   65536
#define NCLS   1000
#define NSAMP  4096   // sample = first 4096 rows
#define CAP    1024   // candidate buffer per patch
#define PRESEL 64     // bf16-score preselection width
#define TAUINV 50.0f  // 1/0.02

__device__ __forceinline__ unsigned short f2bf(float f){
  unsigned b = __float_as_uint(f);
  b += 0x7FFFu + ((b >> 16) & 1u);      // RNE
  return (unsigned short)(b >> 16);
}
__device__ __forceinline__ unsigned encf(float x){
  unsigned b = __float_as_uint(x);
  return (b & 0x80000000u) ? ~b : (b | 0x80000000u);
}
__device__ __forceinline__ float decf(unsigned k){
  unsigned b = (k & 0x80000000u) ? (k & 0x7FFFFFFFu) : ~k;
  return __uint_as_float(b);
}
__device__ __forceinline__ void gload16(const void* g, void* l){
  __builtin_amdgcn_global_load_lds(
      (const __attribute__((address_space(1))) unsigned int*)g,
      (__attribute__((address_space(3))) unsigned int*)l, 16, 0, 0);
}
__device__ __forceinline__ uint4 pack8(float4 a, float4 b){
  uint4 u;
  u.x = (unsigned)f2bf(a.x) | ((unsigned)f2bf(a.y) << 16);
  u.y = (unsigned)f2bf(a.z) | ((unsigned)f2bf(a.w) << 16);
  u.z = (unsigned)f2bf(b.x) | ((unsigned)f2bf(b.y) << 16);
  u.w = (unsigned)f2bf(b.z) | ((unsigned)f2bf(b.w) << 16);
  return u;
}

// ---------------- protos + anchors_bf16 (pre-swizzled) ----------------
__global__ __launch_bounds__(256) void proto_kernel(
    const float* __restrict__ anchors, const float* __restrict__ sums,
    const float* __restrict__ counts, float* __restrict__ protos,
    unsigned short* __restrict__ anchors_bf)
{
  int c = blockIdx.x, t = threadIdx.x;
  if (c >= NCLS){  // pad rows 1000..1023 with zeros
    for (int j = 0; j < 3; ++j) anchors_bf[(size_t)c*DIM + t + j*256] = 0;
    return;
  }
  __shared__ float wv[4]; __shared__ float bc;
  float cnt = fmaxf(counts[c], 1.0f);
  float v[3];
  #pragma unroll
  for (int j = 0; j < 3; ++j) v[j] = sums[(size_t)c*DIM + t + j*256] / cnt;
  float ss = v[0]*v[0] + v[1]*v[1] + v[2]*v[2];
  for (int off = 32; off > 0; off >>= 1) ss += __shfl_down(ss, off, 64);
  if ((t & 63) == 0) wv[t >> 6] = ss;
  __syncthreads();
  if (t == 0) bc = wv[0] + wv[1] + wv[2] + wv[3];
  __syncthreads();
  float rn = 1.0f / fmaxf(sqrtf(bc), 1e-12f);
  __syncthreads();
  float pr[3];
  #pragma unroll
  for (int j = 0; j < 3; ++j){
    int d = t + j*256;
    float a = anchors[(size_t)c*DIM + d];
    pr[j] = a + v[j] * rn;                         // ALPHA = 1.0
    int dd = (d & ~63) | ((((d >> 3) ^ c) & 7) << 3) | (d & 7);
    anchors_bf[(size_t)c*DIM + dd] = f2bf(a);
  }
  ss = pr[0]*pr[0] + pr[1]*pr[1] + pr[2]*pr[2];
  for (int off = 32; off > 0; off >>= 1) ss += __shfl_down(ss, off, 64);
  if ((t & 63) == 0) wv[t >> 6] = ss;
  __syncthreads();
  if (t == 0) bc = wv[0] + wv[1] + wv[2] + wv[3];
  __syncthreads();
  float rn2 = 1.0f / fmaxf(sqrtf(bc), 1e-12f);
  #pragma unroll
  for (int j = 0; j < 3; ++j) protos[(size_t)c*DIM + t + j*256] = pr[j] * rn2;
}

// ---------------- patches f32 working copy ----------------
__global__ __launch_bounds__(256) void prep_patches(
    const float* __restrict__ tp, float* __restrict__ pc)
{
  size_t i = (size_t)blockIdx.x*256 + threadIdx.x;
  *(float4*)(pc + i*4) = *(const float4*)(tp + i*4);
}

// ---------------- f32 -> bf16 pre-swizzled conversion ----------------
__global__ __launch_bounds__(256) void conv_kernel(
    const float* __restrict__ src, unsigned short* __restrict__ dst)
{
  int id = blockIdx.x*256 + threadIdx.x;   // one per 64-elem block
  int row = id / 12, blk = id % 12;
  const float4* s = (const float4*)(src + (size_t)row*DIM + blk*64);
  unsigned short* drow = dst + (size_t)row*DIM + blk*64;
  int key = row & 7;
  #pragma unroll
  for (int c8 = 0; c8 < 8; ++c8){
    uint4 u = pack8(s[c8*2], s[c8*2+1]);
    *(uint4*)(drow + (c8 ^ key)*8) = u;
  }
}

// ---------------- initial K-major swizzled patch slab [12][2048][64] ----------------
__global__ __launch_bounds__(192) void slab_kernel(
    const float* __restrict__ pc, unsigned short* __restrict__ slab)
{
  int b = blockIdx.x, t = threadIdx.x;
  int p = b*2 + (t >= 96 ? 1 : 0);
  int q = (t >= 96) ? t - 96 : t;
  int ks = q >> 3, c8 = q & 7;
  const float* s = pc + (size_t)p*DIM + ks*64 + c8*8;
  uint4 u = pack8(*(const float4*)s, *(const float4*)(s + 4));
  *(uint4*)((char*)slab + (((size_t)ks*NPATCH + p)*128) + ((size_t)(c8 ^ (p & 7))*16)) = u;
}

// ---------------- unified MFMA GEMM (double-buffered 2-phase) ----------------
// MODE 0: A=mbf rows rowbase.., NT tiles/block, filter >= th, append idx+score
// MODE 1: A=mbf rows 0..4095, write sims_sample[patch][node]
// MODE 2: A=anchors_bf (rows>=1000 zero), atomicMax evidence
template<int MODE, int NT>
__global__ __launch_bounds__(256, 2) void gemm_kernel(
    const unsigned short* __restrict__ Abf, int rowbase,
    const unsigned short* __restrict__ Bslab,
    const float* __restrict__ thresholds,
    int* __restrict__ counters,
    int* __restrict__ cand_idx,
    float* __restrict__ cand_score,
    float* __restrict__ sims_sample,
    unsigned* __restrict__ ev_key,
    const int* __restrict__ active)
{
  if (*active == 0) return;
  __shared__ __align__(16) unsigned short Al[2][128*64];
  __shared__ __align__(16) unsigned short Bl[2][128*64];
  int b = blockIdx.x, nwg = gridDim.x;
  int wg = (b & 7)*(nwg >> 3) + (b >> 3);   // XCD-chunked swizzle (nwg%8==0)
  int mt0 = (wg >> 4) * NT, pt = wg & 15;
  int t = threadIdx.x, w = t >> 6, lane = t & 63, l15 = lane & 15, l4 = lane >> 4;
  int wr = w >> 1, wc = w & 1;
  int pbase = pt*128;
  int srow = w*8 + (lane >> 3);
  int scol = (lane & 7)*16;

  const char* Ab = (const char*)Abf;
  const char* Bb = (const char*)Bslab;

  float thv[4];
  if (MODE == 0){
    #pragma unroll
    for (int g = 0; g < 4; ++g) thv[g] = thresholds[pbase + wc*64 + g*16 + l15];
  }

  // stage step s (tile s/12, K-slice s%12) into LDS buffer bsel
  auto STAGE = [&](int s, int bsel){
    int tile = s / 12, ks = s % 12;
    size_t arow0 = (size_t)rowbase + ((size_t)(mt0 + tile))*128;
    #pragma unroll
    for (int i = 0; i < 4; ++i){
      const void* ga = Ab + ((arow0 + srow + i*32)*(size_t)(DIM*2)) + ks*128 + scol;
      gload16(ga, (char*)Al[bsel] + i*4096 + w*1024);
      const void* gb = Bb + (((size_t)ks*NPATCH + pbase)*128) + i*4096 + w*1024 + lane*16;
      gload16(gb, (char*)Bl[bsel] + i*4096 + w*1024);
    }
  };

  f32x4 acc[4][4];
  #pragma unroll
  for (int x = 0; x < 4; ++x)
    #pragma unroll
    for (int y = 0; y < 4; ++y) acc[x][y] = (f32x4){0.f, 0.f, 0.f, 0.f};

  STAGE(0, 0);
  asm volatile("s_waitcnt vmcnt(0)" ::: "memory");
  __builtin_amdgcn_s_barrier();
  __builtin_amdgcn_sched_barrier(0);

  const int NSTEP = NT * 12;
  for (int s = 0; s < NSTEP; ++s){
    int cur = s & 1;
    if (s + 1 < NSTEP) STAGE(s + 1, cur ^ 1);   // prefetch hides under MFMA

    short8 af[2][4], bf_[2][4];
    #pragma unroll
    for (int kk = 0; kk < 2; ++kk){
      #pragma unroll
      for (int ng = 0; ng < 4; ++ng){
        int row = wr*64 + ng*16 + l15;
        int slot = (kk*4 + l4) ^ (row & 7);
        af[kk][ng] = *(const short8*)((const char*)Al[cur] + row*128 + slot*16);
      }
      #pragma unroll
      for (int g = 0; g < 4; ++g){
        int row = wc*64 + g*16 + l15;
        int slot = (kk*4 + l4) ^ (row & 7);
        bf_[kk][g] = *(const short8*)((const char*)Bl[cur] + row*128 + slot*16);
      }
    }
    #pragma unroll
    for (int kk = 0; kk < 2; ++kk)
      #pragma unroll
      for (int ng = 0; ng < 4; ++ng)
        #pragma unroll
        for (int g = 0; g < 4; ++g)
          acc[ng][g] = __builtin_amdgcn_mfma_f32_16x16x32_bf16(af[kk][ng], bf_[kk][g], acc[ng][g], 0, 0, 0);

    if ((s % 12) == 11){
      int tile = s / 12;
      int nodebase = rowbase + (mt0 + tile)*128 + wr*64;
      if (MODE == 0){
        #pragma unroll
        for (int g = 0; g < 4; ++g){
          int patch = pbase + wc*64 + g*16 + l15;
          float th = thv[g];
          #pragma unroll
          for (int ng = 0; ng < 4; ++ng){
            #pragma unroll
            for (int i = 0; i < 4; ++i){
              float v = acc[ng][g][i];
              if (v >= th){
                int node = nodebase + ng*16 + l4*4 + i;
                int pos = atomicAdd(&counters[patch], 1);
                if (pos < CAP){
                  cand_idx[(size_t)patch*CAP + pos]   = node;
                  cand_score[(size_t)patch*CAP + pos] = v;
                }
              }
            }
          }
        }
      } else if (MODE == 1){
        #pragma unroll
        for (int g = 0; g < 4; ++g){
          int patch = pbase + wc*64 + g*16 + l15;
          #pragma unroll
          for (int ng = 0; ng < 4; ++ng){
            int col = nodebase + ng*16 + l4*4;
            *(f32x4*)(sims_sample + (size_t)patch*NSAMP + col) = acc[ng][g];
          }
        }
      } else {
        #pragma unroll
        for (int g = 0; g < 4; ++g){
          int patch = pbase + wc*64 + g*16 + l15;
          float m = -3e38f; bool any = false;
          #pragma unroll
          for (int ng = 0; ng < 4; ++ng){
            #pragma unroll
            for (int i = 0; i < 4; ++i){
              int a = nodebase + ng*16 + l4*4 + i;
              if (a < NCLS){ m = fmaxf(m, acc[ng][g][i]); any = true; }
            }
          }
          if (any) atomicMax(&ev_key[patch], encf(m));
        }
      }
      #pragma unroll
      for (int x = 0; x < 4; ++x)
        #pragma unroll
        for (int y = 0; y < 4; ++y) acc[x][y] = (f32x4){0.f, 0.f, 0.f, 0.f};
    }

    asm volatile("s_waitcnt vmcnt(0)" ::: "memory");
    __builtin_amdgcn_s_barrier();
    __builtin_amdgcn_sched_barrier(0);
  }
}

// -- threshold = 16th max of sampled sims; seed candidates; init cnt + evk --
__global__ __launch_bounds__(256) void thresh_kernel(
    const float* __restrict__ sims, float* __restrict__ thresholds,
    int* __restrict__ counters, int* __restrict__ cand_idx,
    float* __restrict__ cand_score, unsigned* __restrict__ ev_key,
    const int* __restrict__ active)
{
  if (*active == 0) return;
  __shared__ float s[NSAMP];
  __shared__ float wv[4]; __shared__ int wi[4];
  __shared__ float tv16[16]; __shared__ int ti16[16];
  __shared__ float result;
  __shared__ int lcnt;
  int p = blockIdx.x, t = threadIdx.x;
  const float4* src = (const float4*)(sims + (size_t)p*NSAMP);
  for (int i = t; i < NSAMP/4; i += 256) *(float4*)&s[i*4] = src[i];
  __syncthreads();
  for (int r = 0; r < 16; ++r){
    float v = -3e38f; int idx = 0;
    #pragma unroll
    for (int j = 0; j < 16; ++j){
      int ii = t*16 + j; float x = s[ii];
      if (x > v){ v = x; idx = ii; }
    }
    for (int off = 32; off > 0; off >>= 1){
      float ov = __shfl_down(v, off, 64); int oi = __shfl_down(idx, off, 64);
      if (ov > v || (ov == v && oi < idx)){ v = ov; idx = oi; }
    }
    if ((t & 63) == 0){ wv[t >> 6] = v; wi[t >> 6] = idx; }
    __syncthreads();
    if (t == 0){
      float bv = wv[0]; int bi = wi[0];
      for (int q = 1; q < 4; ++q)
        if (wv[q] > bv || (wv[q] == bv && wi[q] < bi)){ bv = wv[q]; bi = wi[q]; }
      s[bi] = -3e38f;
      tv16[r] = bv; ti16[r] = bi;
      if (r == 15) result = bv;
    }
    __syncthreads();
  }
  float th = result;
  if (t == 0){
    thresholds[p] = th;
    ev_key[p] = 0u;                        // evidence key init (pre-gemm2)
    lcnt = 16;
    #pragma unroll
    for (int k = 0; k < 16; ++k){
      cand_idx[(size_t)p*CAP + k]   = ti16[k];
      cand_score[(size_t)p*CAP + k] = tv16[k];
    }
  }
  __syncthreads();
  // ties: remaining sampled values >= th (top-16 already destroyed)
  for (int i = t; i < NSAMP; i += 256){
    float x = s[i];
    if (x >= th){
      int pos = atomicAdd(&lcnt, 1);
      if (pos < CAP){
        cand_idx[(size_t)p*CAP + pos]   = i;
        cand_score[(size_t)p*CAP + pos] = x;
      }
    }
  }
  __syncthreads();
  if (t == 0) counters[p] = lcnt < CAP ? lcnt : CAP;
}

// -- bf16-top-64 preselect -> exact rescore -> exact top-50 -> message + slab --
__global__ __launch_bounds__(256) void msg_kernel(
    const int* __restrict__ counters, const int* __restrict__ cand_idx,
    const float* __restrict__ cand_score, const float* __restrict__ memf,
    float* __restrict__ pc, unsigned short* __restrict__ slab,
    const int* __restrict__ active)
{
  if (*active == 0) return;
  __shared__ float sc[CAP]; __shared__ int si[CAP];
  __shared__ __align__(16) float gl[DIM];
  __shared__ int pi_[PRESEL]; __shared__ float exv[PRESEL];
  __shared__ float selv[50]; __shared__ int seli[50]; __shared__ float attn[50];
  __shared__ float wv[4]; __shared__ int wi[4];
  __shared__ float bc;
  int p = blockIdx.x, t = threadIdx.x;
  int n = counters[p]; if (n > CAP) n = CAP;
  #pragma unroll
  for (int j = 0; j < 3; ++j) gl[t + j*256] = pc[(size_t)p*DIM + t + j*256];
  for (int i = t; i < CAP; i += 256){
    sc[i] = (i < n) ? cand_score[(size_t)p*CAP + i] : -3e38f;
    si[i] = (i < n) ? cand_idx[(size_t)p*CAP + i] : 0;
  }
  if (t < PRESEL) exv[t] = -3e38f;
  __syncthreads();
  // phase 1: top-PRESEL by stored bf16 MFMA score
  int NS = n < PRESEL ? n : PRESEL;
  for (int r = 0; r < NS; ++r){
    float v = -3e38f; int idx = 0;
    #pragma unroll
    for (int j = 0; j < 4; ++j){
      int ii = t*4 + j; float x = sc[ii];
      if (x > v){ v = x; idx = ii; }
    }
    for (int off = 32; off > 0; off >>= 1){
      float ov = __shfl_down(v, off, 64); int oi = __shfl_down(idx, off, 64);
      if (ov > v || (ov == v && oi < idx)){ v = ov; idx = oi; }
    }
    if ((t & 63) == 0){ wv[t >> 6] = v; wi[t >> 6] = idx; }
    __syncthreads();
    if (t == 0){
      float bv = wv[0]; int bi = wi[0];
      for (int q = 1; q < 4; ++q)
        if (wv[q] > bv || (wv[q] == bv && wi[q] < bi)){ bv = wv[q]; bi = wi[q]; }
      pi_[r] = si[bi]; sc[bi] = -3e38f;
    }
    __syncthreads();
  }
  // phase 2: exact f32 rescore of preselected rows
  int w = t >> 6, lane = t & 63;
  for (int i = w; i < NS; i += 4){
    const float* row = memf + (size_t)pi_[i]*DIM;
    float s = 0.f;
    #pragma unroll
    for (int j = 0; j < 12; ++j){
      int d = lane + j*64;
      s += row[d] * gl[d];
    }
    for (int off = 32; off > 0; off >>= 1) s += __shfl_down(s, off, 64);
    if (lane == 0) exv[i] = s;
  }
  __syncthreads();
  // phase 3: exact top-50
  int K = NS < 50 ? NS : 50;
  for (int r = 0; r < K; ++r){
    float v = (t < PRESEL) ? exv[t] : -3e38f; int idx = (t < PRESEL) ? t : 0;
    for (int off = 32; off > 0; off >>= 1){
      float ov = __shfl_down(v, off, 64); int oi = __shfl_down(idx, off, 64);
      if (ov > v || (ov == v && oi < idx)){ v = ov; idx = oi; }
    }
    if ((t & 63) == 0){ wv[t >> 6] = v; wi[t >> 6] = idx; }
    __syncthreads();
    if (t == 0){
      float bv = wv[0]; int bi = wi[0];
      for (int q = 1; q < 4; ++q)
        if (wv[q] > bv || (wv[q] == bv && wi[q] < bi)){ bv = wv[q]; bi = wi[q]; }
      selv[r] = bv; seli[r] = pi_[bi]; exv[bi] = -3e38f;
    }
    __syncthreads();
  }
  if (t < K) attn[t] = __expf((selv[t] - selv[0]) * TAUINV);
  __syncthreads();
  if (t == 0){ float s = 0.f; for (int k = 0; k < K; ++k) s += attn[k]; bc = s; }
  __syncthreads();
  float inv = 1.0f / bc;
  int d0 = t, d1 = t + 256, d2 = t + 512;
  float a0 = gl[d0], a1 = gl[d1], a2 = gl[d2];
  for (int k = 0; k < K; ++k){
    float a = attn[k] * inv;
    const float* row = memf + (size_t)seli[k]*DIM;
    a0 += a * row[d0]; a1 += a * row[d1]; a2 += a * row[d2];
  }
  float ss = a0*a0 + a1*a1 + a2*a2;
  for (int off = 32; off > 0; off >>= 1) ss += __shfl_down(ss, off, 64);
  if ((t & 63) == 0) wv[t >> 6] = ss;
  __syncthreads();
  if (t == 0) bc = wv[0] + wv[1] + wv[2] + wv[3];
  __syncthreads();
  float rn = 1.0f / fmaxf(sqrtf(bc), 1e-12f);
  a0 *= rn; a1 *= rn; a2 *= rn;
  float* orow = pc + (size_t)p*DIM;
  orow[d0] = a0; orow[d1] = a1; orow[d2] = a2;
  // fused slab update: route new row through gl, repack swizzled bf16
  __syncthreads();
  gl[d0] = a0; gl[d1] = a1; gl[d2] = a2;
  __syncthreads();
  if (t < 96){
    int ks2 = t >> 3, c8 = t & 7;
    const float* sblk = &gl[ks2*64 + c8*8];
    uint4 u = pack8(*(const float4*)sblk, *(const float4*)(sblk + 4));
    *(uint4*)((char*)slab + (((size_t)ks2*NPATCH + p)*128) + ((size_t)(c8 ^ (p & 7))*16)) = u;
  }
}

// ---------------- evidence softmax stats + weighted pooling partials ----------------
__global__ __launch_bounds__(256) void pl2_kernel(
    const unsigned* __restrict__ ev_key, const float* __restrict__ pc,
    float* __restrict__ g_part, const int* __restrict__ active)
{
  if (*active == 0) return;
  __shared__ float wv[4]; __shared__ float bc;
  int t = threadIdx.x;
  // stats over all 2048 ev keys (redundant per block, trivial cost)
  float m = -3e38f;
  for (int i = t; i < NPATCH; i += 256) m = fmaxf(m, decf(ev_key[i]));
  for (int off = 32; off > 0; off >>= 1) m = fmaxf(m, __shfl_down(m, off, 64));
  if ((t & 63) == 0) wv[t >> 6] = m;
  __syncthreads();
  if (t == 0) bc = fmaxf(fmaxf(wv[0], wv[1]), fmaxf(wv[2], wv[3]));
  __syncthreads();
  float M = bc;
  __syncthreads();
  float s = 0.f;
  for (int i = t; i < NPATCH; i += 256) s += __expf((decf(ev_key[i]) - M) * TAUINV);
  for (int off = 32; off > 0; off >>= 1) s += __shfl_down(s, off, 64);
  if ((t & 63) == 0) wv[t >> 6] = s;
  __syncthreads();
  if (t == 0) bc = wv[0] + wv[1] + wv[2] + wv[3];
  __syncthreads();
  float invS = 1.0f / bc;
  int pbase = blockIdx.x * 64;
  float a0 = 0.f, a1 = 0.f, a2 = 0.f;
  for (int i = 0; i < 64; ++i){
    int p = pbase + i;
    float wgt = __expf((decf(ev_key[p]) - M) * TAUINV) * invS;
    const float* row = pc + (size_t)p*DIM;
    a0 += wgt * row[t]; a1 += wgt * row[t + 256]; a2 += wgt * row[t + 512];
  }
  g_part[blockIdx.x*DIM + t]       = a0;
  g_part[blockIdx.x*DIM + t + 256] = a1;
  g_part[blockIdx.x*DIM + t + 512] = a2;
}

// ------- logits + entropy + commit (INIT: g=tg; else reduce g_part + norm) -------
template<bool INIT>
__global__ __launch_bounds__(256) void cm_kernel(
    const float* __restrict__ gsrc, const float* __restrict__ protos,
    float* __restrict__ logits_cur, int* __restrict__ step, int* __restrict__ active)
{
  if (!INIT && *active == 0) return;
  __shared__ __align__(16) float gl[DIM];
  __shared__ float lg[NCLS];
  __shared__ float wv[4]; __shared__ float bc;
  int t = threadIdx.x;
  if (INIT){
    #pragma unroll
    for (int j = 0; j < 3; ++j) gl[t + j*256] = gsrc[t + j*256];
  } else {
    float gv[3]; float ss = 0.f;
    #pragma unroll
    for (int j = 0; j < 3; ++j){
      int d = t + j*256;
      float s = 0.f;
      for (int b2 = 0; b2 < 32; ++b2) s += gsrc[b2*DIM + d];
      gv[j] = s; ss += s*s;
    }
    for (int off = 32; off > 0; off >>= 1) ss += __shfl_down(ss, off, 64);
    if ((t & 63) == 0) wv[t >> 6] = ss;
    __syncthreads();
    if (t == 0) bc = wv[0] + wv[1] + wv[2] + wv[3];
    __syncthreads();
    float rn = 1.0f / fmaxf(sqrtf(bc), 1e-12f);
    #pragma unroll
    for (int j = 0; j < 3; ++j) gl[t + j*256] = gv[j] * rn;
  }
  __syncthreads();
  for (int c = t; c < NCLS; c += 256){
    const float4* pr = (const float4*)(protos + (size_t)c*DIM);
    float s = 0.f;
    #pragma unroll 4
    for (int d4 = 0; d4 < DIM/4; ++d4){
      float4 pv = pr[d4];
      float4 gv = *(const float4*)&gl[d4*4];
      s += gv.x*pv.x + gv.y*pv.y + gv.z*pv.z + gv.w*pv.w;
    }
    float L = 100.0f * s;
    lg[c] = L; logits_cur[c] = L;
  }
  __syncthreads();
  float m = -3e38f;
  for (int c = t; c < NCLS; c += 256) m = fmaxf(m, lg[c]);
  for (int off = 32; off > 0; off >>= 1) m = fmaxf(m, __shfl_down(m, off, 64));
  if ((t & 63) == 0) wv[t >> 6] = m;
  __syncthreads();
  if (t == 0) bc = fmaxf(fmaxf(wv[0], wv[1]), fmaxf(wv[2], wv[3]));
  __syncthreads();
  float M = bc;
  __syncthreads();
  float s = 0.f;
  for (int c = t; c < NCLS; c += 256) s += __expf(lg[c] - M);
  for (int off = 32; off > 0; off >>= 1) s += __shfl_down(s, off, 64);
  if ((t & 63) == 0) wv[t >> 6] = s;
  __syncthreads();
  if (t == 0) bc = wv[0] + wv[1] + wv[2] + wv[3];
  __syncthreads();
  float S = bc;
  __syncthreads();
  float hp = 0.f;
  for (int c = t; c < NCLS; c += 256){
    float pcl = __expf(lg[c] - M) / S;
    hp += pcl * __logf(pcl + 1e-10f);
  }
  for (int off = 32; off > 0; off >>= 1) hp += __shfl_down(hp, off, 64);
  if ((t & 63) == 0) wv[t >> 6] = hp;
  __syncthreads();
  if (t == 0){
    float H = -(wv[0] + wv[1] + wv[2] + wv[3]);
    if (INIT){ *step = 0; *active = (H > 0.8f) ? 1 : 0; }
    else     { *step = *step + 1; *active = (H > 0.8f) ? 1 : 0; }
  }
}

// ---------------- publish ----------------
__global__ void pub_kernel(const float* __restrict__ logits_cur, const int* __restrict__ step,
                           float* __restrict__ out)
{
  int i = blockIdx.x*256 + threadIdx.x;
  if (i < NCLS) out[i] = logits_cur[i];
  else if (i == NCLS) out[i] = (float)(*step);
}

extern "C" void kernel_launch(void* const* d_in, const int* in_sizes, int n_in,
                              void* d_out, int out_size, void* d_ws, size_t ws_size,
                              hipStream_t stream)
{
  (void)in_sizes; (void)n_in; (void)out_size; (void)ws_size;
  const float* tg  = (const float*)d_in[0];   // [1,768]
  const float* tp  = (const float*)d_in[1];   // [2048,768]
  const float* mem = (const float*)d_in[2];   // [65536,768]
  const float* anc = (const float*)d_in[3];   // [1000,768]
  const float* cs  = (const float*)d_in[4];   // [1000,768]
  const float* cc  = (const float*)d_in[5];   // [1000]

  char* ws = (char*)d_ws;
  auto al = [](size_t x){ return (x + 255) & ~(size_t)255; };
  size_t OFF_PC   = 0;
  size_t OFF_PROT = al(OFF_PC   + (size_t)NPATCH*DIM*4);
  size_t OFF_ABF  = al(OFF_PROT + (size_t)NCLS*DIM*4);
  size_t OFF_MBF  = al(OFF_ABF  + (size_t)1024*DIM*2);
  size_t OFF_SLAB = al(OFF_MBF  + (size_t)NMEM*DIM*2);
  size_t OFF_SS   = al(OFF_SLAB + (size_t)NPATCH*DIM*2);
  size_t OFF_THR  = al(OFF_SS   + (size_t)NPATCH*NSAMP*4);
  size_t OFF_CNT  = al(OFF_THR  + (size_t)NPATCH*4);
  size_t OFF_CI   = al(OFF_CNT  + (size_t)NPATCH*4);
  size_t OFF_CSC  = al(OFF_CI   + (size_t)NPATCH*CAP*4);
  size_t OFF_EV   = al(OFF_CSC  + (size_t)NPATCH*CAP*4);
  size_t OFF_GP   = al(OFF_EV   + (size_t)NPATCH*4);
  size_t OFF_LC   = al(OFF_GP   + (size_t)32*DIM*4);
  size_t OFF_STEP = al(OFF_LC   + (size_t)NCLS*4);

  float*          pc      = (float*)(ws + OFF_PC);
  float*          protos  = (float*)(ws + OFF_PROT);
  unsigned short* abf     = (unsigned short*)(ws + OFF_ABF);
  unsigned short* mbf     = (unsigned short*)(ws + OFF_MBF);
  unsigned short* slab    = (unsigned short*)(ws + OFF_SLAB);
  float*          simss   = (float*)(ws + OFF_SS);
  float*          thr     = (float*)(ws + OFF_THR);
  int*            cnt     = (int*)(ws + OFF_CNT);
  int*            ci      = (int*)(ws + OFF_CI);
  float*          csc     = (float*)(ws + OFF_CSC);
  unsigned*       evk     = (unsigned*)(ws + OFF_EV);
  float*          gp      = (float*)(ws + OFF_GP);
  float*          lc      = (float*)(ws + OFF_LC);
  int*            stepp   = (int*)(ws + OFF_STEP);
  int*            activep = stepp + 1;

  proto_kernel<<<1024, 256, 0, stream>>>(anc, cs, cc, protos, abf);
  prep_patches<<<(NPATCH*DIM/4)/256, 256, 0, stream>>>(tp, pc);
  conv_kernel<<<(NMEM*12)/256, 256, 0, stream>>>(mem, mbf);
  cm_kernel<true><<<1, 256, 0, stream>>>(tg, protos, lc, stepp, activep);
  slab_kernel<<<NPATCH/2, 192, 0, stream>>>(pc, slab);

  for (int it = 0; it < 3; ++it){
    gemm_kernel<1,1><<<(NSAMP/128)*16, 256, 0, stream>>>(mbf, 0, slab, thr, cnt, ci, csc, simss, evk, activep);
    thresh_kernel<<<NPATCH, 256, 0, stream>>>(simss, thr, cnt, ci, csc, evk, activep);
    gemm_kernel<0,4><<<((NMEM-NSAMP)/512)*16, 256, 0, stream>>>(mbf, NSAMP, slab, thr, cnt, ci, csc, simss, evk, activep);
    msg_kernel<<<NPATCH, 256, 0, stream>>>(cnt, ci, csc, mem, pc, slab, activep);
    gemm_kernel<2,1><<<(1024/128)*16, 256, 0, stream>>>(abf, 0, slab, thr, cnt, ci, csc, simss, evk, activep);
    pl2_kernel<<<32, 256, 0, stream>>>(evk, pc, gp, activep);
    cm_kernel<false><<<1, 256, 0, stream>>>(gp, protos, lc, stepp, activep);
  }
  pub_kernel<<<4, 256, 0, stream>>>(lc, stepp, (float*)d_out);
}

// Round 6
// 2239.932 us; speedup vs baseline: 1.2058x; 1.2058x over previous
//
#include <hip/hip_runtime.h>
#include <hip/hip_bf16.h>
#include <stdint.h>

// ContinuousEpisodicVLM: 3-step episodic retrieval loop.
// bf16 MFMA candidate generation (sampled-threshold filter) + bf16-top-64
// preselect + exact f32 rescore + exact top-50 softmax message.
// GEMM: 128x128 tile, BK=64, SINGLE-buffer 32KB LDS (3 blocks/CU — cross-block
// wave overlap is the pipeline; m132 lesson: 64KB dbuf loses occupancy), NT=4
// M-tiles per block to amortize prologue, pre-swizzled global ->
// global_load_lds -> swizzled ds_read_b128 (zero bank conflicts).

typedef __attribute__((ext_vector_type(8))) short short8;
typedef __attribute__((ext_vector_type(4))) float f32x4;

#define DIM    768
#define NPATCH 2048
#define NMEM   65536
#define NCLS   1000
#define NSAMP  4096   // sample = first 4096 rows
#define CAP    1024   // candidate buffer per patch
#define PRESEL 64     // bf16-score preselection width
#define TAUINV 50.0f  // 1/0.02

__device__ __forceinline__ unsigned short f2bf(float f){
  unsigned b = __float_as_uint(f);
  b += 0x7FFFu + ((b >> 16) & 1u);      // RNE
  return (unsigned short)(b >> 16);
}
__device__ __forceinline__ unsigned encf(float x){
  unsigned b = __float_as_uint(x);
  return (b & 0x80000000u) ? ~b : (b | 0x80000000u);
}
__device__ __forceinline__ float decf(unsigned k){
  unsigned b = (k & 0x80000000u) ? (k & 0x7FFFFFFFu) : ~k;
  return __uint_as_float(b);
}
__device__ __forceinline__ void gload16(const void* g, void* l){
  __builtin_amdgcn_global_load_lds(
      (const __attribute__((address_space(1))) unsigned int*)g,
      (__attribute__((address_space(3))) unsigned int*)l, 16, 0, 0);
}
__device__ __forceinline__ uint4 pack8(float4 a, float4 b){
  uint4 u;
  u.x = (unsigned)f2bf(a.x) | ((unsigned)f2bf(a.y) << 16);
  u.y = (unsigned)f2bf(a.z) | ((unsigned)f2bf(a.w) << 16);
  u.z = (unsigned)f2bf(b.x) | ((unsigned)f2bf(b.y) << 16);
  u.w = (unsigned)f2bf(b.z) | ((unsigned)f2bf(b.w) << 16);
  return u;
}

// ---------------- protos + anchors_bf16 (pre-swizzled) ----------------
__global__ __launch_bounds__(256) void proto_kernel(
    const float* __restrict__ anchors, const float* __restrict__ sums,
    const float* __restrict__ counts, float* __restrict__ protos,
    unsigned short* __restrict__ anchors_bf)
{
  int c = blockIdx.x, t = threadIdx.x;
  if (c >= NCLS){  // pad rows 1000..1023 with zeros
    for (int j = 0; j < 3; ++j) anchors_bf[(size_t)c*DIM + t + j*256] = 0;
    return;
  }
  __shared__ float wv[4]; __shared__ float bc;
  float cnt = fmaxf(counts[c], 1.0f);
  float v[3];
  #pragma unroll
  for (int j = 0; j < 3; ++j) v[j] = sums[(size_t)c*DIM + t + j*256] / cnt;
  float ss = v[0]*v[0] + v[1]*v[1] + v[2]*v[2];
  for (int off = 32; off > 0; off >>= 1) ss += __shfl_down(ss, off, 64);
  if ((t & 63) == 0) wv[t >> 6] = ss;
  __syncthreads();
  if (t == 0) bc = wv[0] + wv[1] + wv[2] + wv[3];
  __syncthreads();
  float rn = 1.0f / fmaxf(sqrtf(bc), 1e-12f);
  __syncthreads();
  float pr[3];
  #pragma unroll
  for (int j = 0; j < 3; ++j){
    int d = t + j*256;
    float a = anchors[(size_t)c*DIM + d];
    pr[j] = a + v[j] * rn;                         // ALPHA = 1.0
    int dd = (d & ~63) | ((((d >> 3) ^ c) & 7) << 3) | (d & 7);
    anchors_bf[(size_t)c*DIM + dd] = f2bf(a);
  }
  ss = pr[0]*pr[0] + pr[1]*pr[1] + pr[2]*pr[2];
  for (int off = 32; off > 0; off >>= 1) ss += __shfl_down(ss, off, 64);
  if ((t & 63) == 0) wv[t >> 6] = ss;
  __syncthreads();
  if (t == 0) bc = wv[0] + wv[1] + wv[2] + wv[3];
  __syncthreads();
  float rn2 = 1.0f / fmaxf(sqrtf(bc), 1e-12f);
  #pragma unroll
  for (int j = 0; j < 3; ++j) protos[(size_t)c*DIM + t + j*256] = pr[j] * rn2;
}

// ---------------- patches f32 working copy ----------------
__global__ __launch_bounds__(256) void prep_patches(
    const float* __restrict__ tp, float* __restrict__ pc)
{
  size_t i = (size_t)blockIdx.x*256 + threadIdx.x;
  *(float4*)(pc + i*4) = *(const float4*)(tp + i*4);
}

// ---------------- f32 -> bf16 pre-swizzled conversion ----------------
__global__ __launch_bounds__(256) void conv_kernel(
    const float* __restrict__ src, unsigned short* __restrict__ dst)
{
  int id = blockIdx.x*256 + threadIdx.x;   // one per 64-elem block
  int row = id / 12, blk = id % 12;
  const float4* s = (const float4*)(src + (size_t)row*DIM + blk*64);
  unsigned short* drow = dst + (size_t)row*DIM + blk*64;
  int key = row & 7;
  #pragma unroll
  for (int c8 = 0; c8 < 8; ++c8){
    uint4 u = pack8(s[c8*2], s[c8*2+1]);
    *(uint4*)(drow + (c8 ^ key)*8) = u;
  }
}

// ---------------- initial K-major swizzled patch slab [12][2048][64] ----------------
__global__ __launch_bounds__(192) void slab_kernel(
    const float* __restrict__ pc, unsigned short* __restrict__ slab)
{
  int b = blockIdx.x, t = threadIdx.x;
  int p = b*2 + (t >= 96 ? 1 : 0);
  int q = (t >= 96) ? t - 96 : t;
  int ks = q >> 3, c8 = q & 7;
  const float* s = pc + (size_t)p*DIM + ks*64 + c8*8;
  uint4 u = pack8(*(const float4*)s, *(const float4*)(s + 4));
  *(uint4*)((char*)slab + (((size_t)ks*NPATCH + p)*128) + ((size_t)(c8 ^ (p & 7))*16)) = u;
}

// ---------------- unified MFMA GEMM (single-buffer, NT tiles/block) ----------------
// MODE 0: A=mbf rows rowbase.., filter >= th, append idx+score
// MODE 1: A=mbf rows 0..4095, write sims_sample[patch][node]
// MODE 2: A=anchors_bf (rows>=1000 zero), atomicMax evidence
template<int MODE, int NT>
__global__ __launch_bounds__(256, 3) void gemm_kernel(
    const unsigned short* __restrict__ Abf, int rowbase,
    const unsigned short* __restrict__ Bslab,
    const float* __restrict__ thresholds,
    int* __restrict__ counters,
    int* __restrict__ cand_idx,
    float* __restrict__ cand_score,
    float* __restrict__ sims_sample,
    unsigned* __restrict__ ev_key,
    const int* __restrict__ active)
{
  if (*active == 0) return;
  __shared__ __align__(16) unsigned short Al[128*64];
  __shared__ __align__(16) unsigned short Bl[128*64];
  int b = blockIdx.x, nwg = gridDim.x;
  int wg = (b & 7)*(nwg >> 3) + (b >> 3);   // XCD-chunked swizzle (nwg%8==0)
  int mt0 = (wg >> 4) * NT, pt = wg & 15;
  int t = threadIdx.x, w = t >> 6, lane = t & 63, l15 = lane & 15, l4 = lane >> 4;
  int wr = w >> 1, wc = w & 1;
  int pbase = pt*128;
  int srow = w*8 + (lane >> 3);
  int scol = (lane & 7)*16;

  const char* Ab = (const char*)Abf;
  const char* Bb = (const char*)Bslab;

  float thv[4];
  if (MODE == 0){
    #pragma unroll
    for (int g = 0; g < 4; ++g) thv[g] = thresholds[pbase + wc*64 + g*16 + l15];
  }

  f32x4 acc[4][4];
  #pragma unroll
  for (int x = 0; x < 4; ++x)
    #pragma unroll
    for (int y = 0; y < 4; ++y) acc[x][y] = (f32x4){0.f, 0.f, 0.f, 0.f};

  const int NSTEP = NT * 12;
  for (int s = 0; s < NSTEP; ++s){
    int tile = s / 12, ks = s % 12;
    if (s) __syncthreads();                 // prev ds_reads done before overwrite
    size_t arow0 = (size_t)rowbase + ((size_t)(mt0 + tile))*128;
    #pragma unroll
    for (int i = 0; i < 4; ++i){
      const void* ga = Ab + ((arow0 + srow + i*32)*(size_t)(DIM*2)) + ks*128 + scol;
      gload16(ga, (char*)Al + i*4096 + w*1024);
      const void* gb = Bb + (((size_t)ks*NPATCH + pbase)*128) + i*4096 + w*1024 + lane*16;
      gload16(gb, (char*)Bl + i*4096 + w*1024);
    }
    __syncthreads();                        // compiler drains vmcnt before barrier

    short8 af[2][4], bf_[2][4];
    #pragma unroll
    for (int kk = 0; kk < 2; ++kk){
      #pragma unroll
      for (int ng = 0; ng < 4; ++ng){
        int row = wr*64 + ng*16 + l15;
        int slot = (kk*4 + l4) ^ (row & 7);
        af[kk][ng] = *(const short8*)((const char*)Al + row*128 + slot*16);
      }
      #pragma unroll
      for (int g = 0; g < 4; ++g){
        int row = wc*64 + g*16 + l15;
        int slot = (kk*4 + l4) ^ (row & 7);
        bf_[kk][g] = *(const short8*)((const char*)Bl + row*128 + slot*16);
      }
    }
    #pragma unroll
    for (int kk = 0; kk < 2; ++kk)
      #pragma unroll
      for (int ng = 0; ng < 4; ++ng)
        #pragma unroll
        for (int g = 0; g < 4; ++g)
          acc[ng][g] = __builtin_amdgcn_mfma_f32_16x16x32_bf16(af[kk][ng], bf_[kk][g], acc[ng][g], 0, 0, 0);

    if (ks == 11){
      int nodebase = rowbase + (mt0 + tile)*128 + wr*64;
      if (MODE == 0){
        #pragma unroll
        for (int g = 0; g < 4; ++g){
          int patch = pbase + wc*64 + g*16 + l15;
          float th = thv[g];
          #pragma unroll
          for (int ng = 0; ng < 4; ++ng){
            #pragma unroll
            for (int i = 0; i < 4; ++i){
              float v = acc[ng][g][i];
              if (v >= th){
                int node = nodebase + ng*16 + l4*4 + i;
                int pos = atomicAdd(&counters[patch], 1);
                if (pos < CAP){
                  cand_idx[(size_t)patch*CAP + pos]   = node;
                  cand_score[(size_t)patch*CAP + pos] = v;
                }
              }
            }
          }
        }
      } else if (MODE == 1){
        #pragma unroll
        for (int g = 0; g < 4; ++g){
          int patch = pbase + wc*64 + g*16 + l15;
          #pragma unroll
          for (int ng = 0; ng < 4; ++ng){
            int col = nodebase + ng*16 + l4*4;
            *(f32x4*)(sims_sample + (size_t)patch*NSAMP + col) = acc[ng][g];
          }
        }
      } else {
        #pragma unroll
        for (int g = 0; g < 4; ++g){
          int patch = pbase + wc*64 + g*16 + l15;
          float m = -3e38f; bool any = false;
          #pragma unroll
          for (int ng = 0; ng < 4; ++ng){
            #pragma unroll
            for (int i = 0; i < 4; ++i){
              int a = nodebase + ng*16 + l4*4 + i;
              if (a < NCLS){ m = fmaxf(m, acc[ng][g][i]); any = true; }
            }
          }
          if (any) atomicMax(&ev_key[patch], encf(m));
        }
      }
      if (tile + 1 < NT){
        #pragma unroll
        for (int x = 0; x < 4; ++x)
          #pragma unroll
          for (int y = 0; y < 4; ++y) acc[x][y] = (f32x4){0.f, 0.f, 0.f, 0.f};
      }
    }
  }
}

// -- threshold = 16th max of sampled sims; seed candidates; init cnt + evk --
__global__ __launch_bounds__(256) void thresh_kernel(
    const float* __restrict__ sims, float* __restrict__ thresholds,
    int* __restrict__ counters, int* __restrict__ cand_idx,
    float* __restrict__ cand_score, unsigned* __restrict__ ev_key,
    const int* __restrict__ active)
{
  if (*active == 0) return;
  __shared__ float s[NSAMP];
  __shared__ float wv[4]; __shared__ int wi[4];
  __shared__ float tv16[16]; __shared__ int ti16[16];
  __shared__ float result;
  __shared__ int lcnt;
  int p = blockIdx.x, t = threadIdx.x;
  const float4* src = (const float4*)(sims + (size_t)p*NSAMP);
  for (int i = t; i < NSAMP/4; i += 256) *(float4*)&s[i*4] = src[i];
  __syncthreads();
  for (int r = 0; r < 16; ++r){
    float v = -3e38f; int idx = 0;
    #pragma unroll
    for (int j = 0; j < 16; ++j){
      int ii = t*16 + j; float x = s[ii];
      if (x > v){ v = x; idx = ii; }
    }
    for (int off = 32; off > 0; off >>= 1){
      float ov = __shfl_down(v, off, 64); int oi = __shfl_down(idx, off, 64);
      if (ov > v || (ov == v && oi < idx)){ v = ov; idx = oi; }
    }
    if ((t & 63) == 0){ wv[t >> 6] = v; wi[t >> 6] = idx; }
    __syncthreads();
    if (t == 0){
      float bv = wv[0]; int bi = wi[0];
      for (int q = 1; q < 4; ++q)
        if (wv[q] > bv || (wv[q] == bv && wi[q] < bi)){ bv = wv[q]; bi = wi[q]; }
      s[bi] = -3e38f;
      tv16[r] = bv; ti16[r] = bi;
      if (r == 15) result = bv;
    }
    __syncthreads();
  }
  float th = result;
  if (t == 0){
    thresholds[p] = th;
    ev_key[p] = 0u;                        // evidence key init (pre-gemm2)
    lcnt = 16;
    #pragma unroll
    for (int k = 0; k < 16; ++k){
      cand_idx[(size_t)p*CAP + k]   = ti16[k];
      cand_score[(size_t)p*CAP + k] = tv16[k];
    }
  }
  __syncthreads();
  // ties: remaining sampled values >= th (top-16 already destroyed)
  for (int i = t; i < NSAMP; i += 256){
    float x = s[i];
    if (x >= th){
      int pos = atomicAdd(&lcnt, 1);
      if (pos < CAP){
        cand_idx[(size_t)p*CAP + pos]   = i;
        cand_score[(size_t)p*CAP + pos] = x;
      }
    }
  }
  __syncthreads();
  if (t == 0) counters[p] = lcnt < CAP ? lcnt : CAP;
}

// -- bf16-top-64 preselect -> exact rescore -> exact top-50 -> message + slab --
__global__ __launch_bounds__(256) void msg_kernel(
    const int* __restrict__ counters, const int* __restrict__ cand_idx,
    const float* __restrict__ cand_score, const float* __restrict__ memf,
    float* __restrict__ pc, unsigned short* __restrict__ slab,
    const int* __restrict__ active)
{
  if (*active == 0) return;
  __shared__ float sc[CAP]; __shared__ int si[CAP];
  __shared__ __align__(16) float gl[DIM];
  __shared__ int pi_[PRESEL]; __shared__ float exv[PRESEL];
  __shared__ float selv[50]; __shared__ int seli[50]; __shared__ float attn[50];
  __shared__ float wv[4]; __shared__ int wi[4];
  __shared__ float bc;
  int p = blockIdx.x, t = threadIdx.x;
  int n = counters[p]; if (n > CAP) n = CAP;
  #pragma unroll
  for (int j = 0; j < 3; ++j) gl[t + j*256] = pc[(size_t)p*DIM + t + j*256];
  for (int i = t; i < CAP; i += 256){
    sc[i] = (i < n) ? cand_score[(size_t)p*CAP + i] : -3e38f;
    si[i] = (i < n) ? cand_idx[(size_t)p*CAP + i] : 0;
  }
  if (t < PRESEL) exv[t] = -3e38f;
  __syncthreads();
  // phase 1: top-PRESEL by stored bf16 MFMA score
  int NS = n < PRESEL ? n : PRESEL;
  for (int r = 0; r < NS; ++r){
    float v = -3e38f; int idx = 0;
    #pragma unroll
    for (int j = 0; j < 4; ++j){
      int ii = t*4 + j; float x = sc[ii];
      if (x > v){ v = x; idx = ii; }
    }
    for (int off = 32; off > 0; off >>= 1){
      float ov = __shfl_down(v, off, 64); int oi = __shfl_down(idx, off, 64);
      if (ov > v || (ov == v && oi < idx)){ v = ov; idx = oi; }
    }
    if ((t & 63) == 0){ wv[t >> 6] = v; wi[t >> 6] = idx; }
    __syncthreads();
    if (t == 0){
      float bv = wv[0]; int bi = wi[0];
      for (int q = 1; q < 4; ++q)
        if (wv[q] > bv || (wv[q] == bv && wi[q] < bi)){ bv = wv[q]; bi = wi[q]; }
      pi_[r] = si[bi]; sc[bi] = -3e38f;
    }
    __syncthreads();
  }
  // phase 2: exact f32 rescore of preselected rows
  int w = t >> 6, lane = t & 63;
  for (int i = w; i < NS; i += 4){
    const float* row = memf + (size_t)pi_[i]*DIM;
    float s = 0.f;
    #pragma unroll
    for (int j = 0; j < 12; ++j){
      int d = lane + j*64;
      s += row[d] * gl[d];
    }
    for (int off = 32; off > 0; off >>= 1) s += __shfl_down(s, off, 64);
    if (lane == 0) exv[i] = s;
  }
  __syncthreads();
  // phase 3: exact top-50
  int K = NS < 50 ? NS : 50;
  for (int r = 0; r < K; ++r){
    float v = (t < PRESEL) ? exv[t] : -3e38f; int idx = (t < PRESEL) ? t : 0;
    for (int off = 32; off > 0; off >>= 1){
      float ov = __shfl_down(v, off, 64); int oi = __shfl_down(idx, off, 64);
      if (ov > v || (ov == v && oi < idx)){ v = ov; idx = oi; }
    }
    if ((t & 63) == 0){ wv[t >> 6] = v; wi[t >> 6] = idx; }
    __syncthreads();
    if (t == 0){
      float bv = wv[0]; int bi = wi[0];
      for (int q = 1; q < 4; ++q)
        if (wv[q] > bv || (wv[q] == bv && wi[q] < bi)){ bv = wv[q]; bi = wi[q]; }
      selv[r] = bv; seli[r] = pi_[bi]; exv[bi] = -3e38f;
    }
    __syncthreads();
  }
  if (t < K) attn[t] = __expf((selv[t] - selv[0]) * TAUINV);
  __syncthreads();
  if (t == 0){ float s = 0.f; for (int k = 0; k < K; ++k) s += attn[k]; bc = s; }
  __syncthreads();
  float inv = 1.0f / bc;
  int d0 = t, d1 = t + 256, d2 = t + 512;
  float a0 = gl[d0], a1 = gl[d1], a2 = gl[d2];
  for (int k = 0; k < K; ++k){
    float a = attn[k] * inv;
    const float* row = memf + (size_t)seli[k]*DIM;
    a0 += a * row[d0]; a1 += a * row[d1]; a2 += a * row[d2];
  }
  float ss = a0*a0 + a1*a1 + a2*a2;
  for (int off = 32; off > 0; off >>= 1) ss += __shfl_down(ss, off, 64);
  if ((t & 63) == 0) wv[t >> 6] = ss;
  __syncthreads();
  if (t == 0) bc = wv[0] + wv[1] + wv[2] + wv[3];
  __syncthreads();
  float rn = 1.0f / fmaxf(sqrtf(bc), 1e-12f);
  a0 *= rn; a1 *= rn; a2 *= rn;
  float* orow = pc + (size_t)p*DIM;
  orow[d0] = a0; orow[d1] = a1; orow[d2] = a2;
  // fused slab update: route new row through gl, repack swizzled bf16
  __syncthreads();
  gl[d0] = a0; gl[d1] = a1; gl[d2] = a2;
  __syncthreads();
  if (t < 96){
    int ks2 = t >> 3, c8 = t & 7;
    const float* sblk = &gl[ks2*64 + c8*8];
    uint4 u = pack8(*(const float4*)sblk, *(const float4*)(sblk + 4));
    *(uint4*)((char*)slab + (((size_t)ks2*NPATCH + p)*128) + ((size_t)(c8 ^ (p & 7))*16)) = u;
  }
}

// ---------------- evidence softmax stats + weighted pooling partials ----------------
__global__ __launch_bounds__(256) void pl2_kernel(
    const unsigned* __restrict__ ev_key, const float* __restrict__ pc,
    float* __restrict__ g_part, const int* __restrict__ active)
{
  if (*active == 0) return;
  __shared__ float wv[4]; __shared__ float bc;
  int t = threadIdx.x;
  float m = -3e38f;
  for (int i = t; i < NPATCH; i += 256) m = fmaxf(m, decf(ev_key[i]));
  for (int off = 32; off > 0; off >>= 1) m = fmaxf(m, __shfl_down(m, off, 64));
  if ((t & 63) == 0) wv[t >> 6] = m;
  __syncthreads();
  if (t == 0) bc = fmaxf(fmaxf(wv[0], wv[1]), fmaxf(wv[2], wv[3]));
  __syncthreads();
  float M = bc;
  __syncthreads();
  float s = 0.f;
  for (int i = t; i < NPATCH; i += 256) s += __expf((decf(ev_key[i]) - M) * TAUINV);
  for (int off = 32; off > 0; off >>= 1) s += __shfl_down(s, off, 64);
  if ((t & 63) == 0) wv[t >> 6] = s;
  __syncthreads();
  if (t == 0) bc = wv[0] + wv[1] + wv[2] + wv[3];
  __syncthreads();
  float invS = 1.0f / bc;
  int pbase = blockIdx.x * 64;
  float a0 = 0.f, a1 = 0.f, a2 = 0.f;
  for (int i = 0; i < 64; ++i){
    int p = pbase + i;
    float wgt = __expf((decf(ev_key[p]) - M) * TAUINV) * invS;
    const float* row = pc + (size_t)p*DIM;
    a0 += wgt * row[t]; a1 += wgt * row[t + 256]; a2 += wgt * row[t + 512];
  }
  g_part[blockIdx.x*DIM + t]       = a0;
  g_part[blockIdx.x*DIM + t + 256] = a1;
  g_part[blockIdx.x*DIM + t + 512] = a2;
}

// ------- logits + entropy + commit (INIT: g=tg; else reduce g_part + norm) -------
template<bool INIT>
__global__ __launch_bounds__(256) void cm_kernel(
    const float* __restrict__ gsrc, const float* __restrict__ protos,
    float* __restrict__ logits_cur, int* __restrict__ step, int* __restrict__ active)
{
  if (!INIT && *active == 0) return;
  __shared__ __align__(16) float gl[DIM];
  __shared__ float lg[NCLS];
  __shared__ float wv[4]; __shared__ float bc;
  int t = threadIdx.x;
  if (INIT){
    #pragma unroll
    for (int j = 0; j < 3; ++j) gl[t + j*256] = gsrc[t + j*256];
  } else {
    float gv[3]; float ss = 0.f;
    #pragma unroll
    for (int j = 0; j < 3; ++j){
      int d = t + j*256;
      float s = 0.f;
      for (int b2 = 0; b2 < 32; ++b2) s += gsrc[b2*DIM + d];
      gv[j] = s; ss += s*s;
    }
    for (int off = 32; off > 0; off >>= 1) ss += __shfl_down(ss, off, 64);
    if ((t & 63) == 0) wv[t >> 6] = ss;
    __syncthreads();
    if (t == 0) bc = wv[0] + wv[1] + wv[2] + wv[3];
    __syncthreads();
    float rn = 1.0f / fmaxf(sqrtf(bc), 1e-12f);
    #pragma unroll
    for (int j = 0; j < 3; ++j) gl[t + j*256] = gv[j] * rn;
  }
  __syncthreads();
  for (int c = t; c < NCLS; c += 256){
    const float4* pr = (const float4*)(protos + (size_t)c*DIM);
    float s = 0.f;
    #pragma unroll 4
    for (int d4 = 0; d4 < DIM/4; ++d4){
      float4 pv = pr[d4];
      float4 gv = *(const float4*)&gl[d4*4];
      s += gv.x*pv.x + gv.y*pv.y + gv.z*pv.z + gv.w*pv.w;
    }
    float L = 100.0f * s;
    lg[c] = L; logits_cur[c] = L;
  }
  __syncthreads();
  float m = -3e38f;
  for (int c = t; c < NCLS; c += 256) m = fmaxf(m, lg[c]);
  for (int off = 32; off > 0; off >>= 1) m = fmaxf(m, __shfl_down(m, off, 64));
  if ((t & 63) == 0) wv[t >> 6] = m;
  __syncthreads();
  if (t == 0) bc = fmaxf(fmaxf(wv[0], wv[1]), fmaxf(wv[2], wv[3]));
  __syncthreads();
  float M = bc;
  __syncthreads();
  float s = 0.f;
  for (int c = t; c < NCLS; c += 256) s += __expf(lg[c] - M);
  for (int off = 32; off > 0; off >>= 1) s += __shfl_down(s, off, 64);
  if ((t & 63) == 0) wv[t >> 6] = s;
  __syncthreads();
  if (t == 0) bc = wv[0] + wv[1] + wv[2] + wv[3];
  __syncthreads();
  float S = bc;
  __syncthreads();
  float hp = 0.f;
  for (int c = t; c < NCLS; c += 256){
    float pcl = __expf(lg[c] - M) / S;
    hp += pcl * __logf(pcl + 1e-10f);
  }
  for (int off = 32; off > 0; off >>= 1) hp += __shfl_down(hp, off, 64);
  if ((t & 63) == 0) wv[t >> 6] = hp;
  __syncthreads();
  if (t == 0){
    float H = -(wv[0] + wv[1] + wv[2] + wv[3]);
    if (INIT){ *step = 0; *active = (H > 0.8f) ? 1 : 0; }
    else     { *step = *step + 1; *active = (H > 0.8f) ? 1 : 0; }
  }
}

// ---------------- publish ----------------
__global__ void pub_kernel(const float* __restrict__ logits_cur, const int* __restrict__ step,
                           float* __restrict__ out)
{
  int i = blockIdx.x*256 + threadIdx.x;
  if (i < NCLS) out[i] = logits_cur[i];
  else if (i == NCLS) out[i] = (float)(*step);
}

extern "C" void kernel_launch(void* const* d_in, const int* in_sizes, int n_in,
                              void* d_out, int out_size, void* d_ws, size_t ws_size,
                              hipStream_t stream)
{
  (void)in_sizes; (void)n_in; (void)out_size; (void)ws_size;
  const float* tg  = (const float*)d_in[0];   // [1,768]
  const float* tp  = (const float*)d_in[1];   // [2048,768]
  const float* mem = (const float*)d_in[2];   // [65536,768]
  const float* anc = (const float*)d_in[3];   // [1000,768]
  const float* cs  = (const float*)d_in[4];   // [1000,768]
  const float* cc  = (const float*)d_in[5];   // [1000]

  char* ws = (char*)d_ws;
  auto al = [](size_t x){ return (x + 255) & ~(size_t)255; };
  size_t OFF_PC   = 0;
  size_t OFF_PROT = al(OFF_PC   + (size_t)NPATCH*DIM*4);
  size_t OFF_ABF  = al(OFF_PROT + (size_t)NCLS*DIM*4);
  size_t OFF_MBF  = al(OFF_ABF  + (size_t)1024*DIM*2);
  size_t OFF_SLAB = al(OFF_MBF  + (size_t)NMEM*DIM*2);
  size_t OFF_SS   = al(OFF_SLAB + (size_t)NPATCH*DIM*2);
  size_t OFF_THR  = al(OFF_SS   + (size_t)NPATCH*NSAMP*4);
  size_t OFF_CNT  = al(OFF_THR  + (size_t)NPATCH*4);
  size_t OFF_CI   = al(OFF_CNT  + (size_t)NPATCH*4);
  size_t OFF_CSC  = al(OFF_CI   + (size_t)NPATCH*CAP*4);
  size_t OFF_EV   = al(OFF_CSC  + (size_t)NPATCH*CAP*4);
  size_t OFF_GP   = al(OFF_EV   + (size_t)NPATCH*4);
  size_t OFF_LC   = al(OFF_GP   + (size_t)32*DIM*4);
  size_t OFF_STEP = al(OFF_LC   + (size_t)NCLS*4);

  float*          pc      = (float*)(ws + OFF_PC);
  float*          protos  = (float*)(ws + OFF_PROT);
  unsigned short* abf     = (unsigned short*)(ws + OFF_ABF);
  unsigned short* mbf     = (unsigned short*)(ws + OFF_MBF);
  unsigned short* slab    = (unsigned short*)(ws + OFF_SLAB);
  float*          simss   = (float*)(ws + OFF_SS);
  float*          thr     = (float*)(ws + OFF_THR);
  int*            cnt     = (int*)(ws + OFF_CNT);
  int*            ci      = (int*)(ws + OFF_CI);
  float*          csc     = (float*)(ws + OFF_CSC);
  unsigned*       evk     = (unsigned*)(ws + OFF_EV);
  float*          gp      = (float*)(ws + OFF_GP);
  float*          lc      = (float*)(ws + OFF_LC);
  int*            stepp   = (int*)(ws + OFF_STEP);
  int*            activep = stepp + 1;

  proto_kernel<<<1024, 256, 0, stream>>>(anc, cs, cc, protos, abf);
  prep_patches<<<(NPATCH*DIM/4)/256, 256, 0, stream>>>(tp, pc);
  conv_kernel<<<(NMEM*12)/256, 256, 0, stream>>>(mem, mbf);
  cm_kernel<true><<<1, 256, 0, stream>>>(tg, protos, lc, stepp, activep);
  slab_kernel<<<NPATCH/2, 192, 0, stream>>>(pc, slab);

  for (int it = 0; it < 3; ++it){
    gemm_kernel<1,1><<<(NSAMP/128)*16, 256, 0, stream>>>(mbf, 0, slab, thr, cnt, ci, csc, simss, evk, activep);
    thresh_kernel<<<NPATCH, 256, 0, stream>>>(simss, thr, cnt, ci, csc, evk, activep);
    gemm_kernel<0,4><<<((NMEM-NSAMP)/512)*16, 256, 0, stream>>>(mbf, NSAMP, slab, thr, cnt, ci, csc, simss, evk, activep);
    msg_kernel<<<NPATCH, 256, 0, stream>>>(cnt, ci, csc, mem, pc, slab, activep);
    gemm_kernel<2,1><<<(1024/128)*16, 256, 0, stream>>>(abf, 0, slab, thr, cnt, ci, csc, simss, evk, activep);
    pl2_kernel<<<32, 256, 0, stream>>>(evk, pc, gp, activep);
    cm_kernel<false><<<1, 256, 0, stream>>>(gp, protos, lc, stepp, activep);
  }
  pub_kernel<<<4, 256, 0, stream>>>(lc, stepp, (float*)d_out);
}